// Round 3
// baseline (260.826 us; speedup 1.0000x reference)
//
#include <hip/hip_runtime.h>
#include <stdint.h>

#define A_N 65536
#define B_N 16
#define G_N 64
#define FEPS 1e-7f

// ---------------- K1: per-anchor best gt (row argmax, cross-mult) + per-(block,gt) best anchor
// (column argmax, lane-owns-gt) — no division, no atomics in the hot loops ----------------
__global__ __launch_bounds__(256) void dl_pass1(
    const float4* __restrict__ bbox, const float4* __restrict__ gt,
    float* __restrict__ posflag, uint8_t* __restrict__ best_idx,
    unsigned long long* __restrict__ gt_part) {
  const int img = blockIdx.y;
  const int bx  = blockIdx.x;
  const int t   = threadIdx.x;
  const int wave = t >> 6, lane = t & 63;
  const int a = bx * 256 + t;

  __shared__ float4 sg[G_N];
  __shared__ float  sga[G_N];
  __shared__ float4 sa[256];
  __shared__ float  saa[256];
  __shared__ unsigned long long spart[4][G_N];

  float4 p = bbox[img * A_N + a];
  float pa = __fmul_rn(__fsub_rn(p.z, p.x), __fsub_rn(p.w, p.y));
  sa[t] = p; saa[t] = pa;
  if (t < G_N) {
    float4 q0 = gt[img * G_N + t];
    sg[t] = q0;
    sga[t] = __fmul_rn(__fsub_rn(q0.z, q0.x), __fsub_rn(q0.w, q0.y));
  }
  __syncthreads();

  // ---- phase A: row pass (each lane = its anchor, loop over gts) ----
  // argmax by cross-multiplication: inter/den > bi/bd  <=>  inter*bd > bi*den (all positive)
  // pos threshold EXACT: iou > 0.5 <=> sign(2*inter - den) > 0 (RN rounding preserves sign)
  float bi = 0.f, bd = 1.f; int bidx = 0; float posm = -1.f;
  #pragma unroll 4
  for (int g = 0; g < G_N; ++g) {
    float4 q = sg[g];
    float ix1 = fmaxf(p.x, q.x), iy1 = fmaxf(p.y, q.y);
    float ix2 = fminf(p.z, q.z), iy2 = fminf(p.w, q.w);
    float iw = fmaxf(__fsub_rn(ix2, ix1), 0.f);
    float ih = fmaxf(__fsub_rn(iy2, iy1), 0.f);
    float inter = __fmul_rn(iw, ih);
    float den = __fadd_rn(__fsub_rn(__fadd_rn(pa, sga[g]), inter), FEPS);  // exact numpy den
    if (inter * bd > bi * den) { bi = inter; bd = den; bidx = g; }  // strict > keeps first occurrence
    posm = fmaxf(posm, __fmaf_rn(2.f, inter, -den));
  }
  posflag[img * A_N + a] = (posm > 0.f) ? 1.f : 0.f;
  best_idx[img * A_N + a] = (uint8_t)bidx;

  // ---- phase B: column pass (each lane owns gt=lane, loop over this wave's 64 anchors) ----
  float4 q = sg[lane];
  float qa = sga[lane];
  float ci = 0.f, cd = 1.f; int caidx = 0;
  const int base = wave * 64;
  #pragma unroll 4
  for (int j = 0; j < 64; ++j) {
    float4 ap = sa[base + j];          // uniform address within wave -> LDS broadcast
    float aa = saa[base + j];
    float ix1 = fmaxf(ap.x, q.x), iy1 = fmaxf(ap.y, q.y);
    float ix2 = fminf(ap.z, q.z), iy2 = fminf(ap.w, q.w);
    float iw = fmaxf(__fsub_rn(ix2, ix1), 0.f);
    float ih = fmaxf(__fsub_rn(iy2, iy1), 0.f);
    float inter = __fmul_rn(iw, ih);
    float den = __fadd_rn(__fsub_rn(__fadd_rn(aa, qa), inter), FEPS);
    if (inter * cd > ci * den) { ci = inter; cd = den; caidx = base + j; }
  }
  // comparable scalar key: approx ratio bits (1-ulp rcp; flips only exact near-ties)
  float ratio = ci * __builtin_amdgcn_rcpf(cd);
  unsigned long long key = ((unsigned long long)__float_as_uint(ratio) << 32)
                         | (unsigned)~(unsigned)(bx * 256 + caidx);  // smaller global idx wins ties
  spart[wave][lane] = key;
  __syncthreads();
  if (t < G_N) {
    unsigned long long m = spart[0][t];
    if (spart[1][t] > m) m = spart[1][t];
    if (spart[2][t] > m) m = spart[2][t];
    if (spart[3][t] > m) m = spart[3][t];
    gt_part[(((size_t)(img << 8) | bx) << 6) | t] = m;  // coalesced 512B store
  }
}

// ---------------- K2: reduce per-block gt keys, force best anchor per GT positive ----------------
__global__ __launch_bounds__(64) void dl_force(const unsigned long long* __restrict__ gt_part,
                                               float* __restrict__ posflag) {
  const int p = blockIdx.x;          // 0..1023 = (img, g)
  const int img = p >> 6, g = p & 63;
  const int t = threadIdx.x;
  unsigned long long m = 0ull;
  #pragma unroll
  for (int j = 0; j < 4; ++j) {
    unsigned long long v = gt_part[(((size_t)(img << 8) | (t + j * 64)) << 6) | g];
    if (v > m) m = v;
  }
  for (int o = 32; o; o >>= 1) {
    unsigned long long other = __shfl_down(m, o);
    if (other > m) m = other;
  }
  if (t == 0) {
    // all-zero column: every partial has ratio bits 0, max low-word = ~0 -> anchor 0 (numpy argmax)
    uint32_t a = ~(uint32_t)(m & 0xFFFFFFFFull);
    posflag[(size_t)img * A_N + a] = 2.0f;  // > 0.5 => positive; best_idx untouched
  }
}

// ---------------- K3: focal loss, DIoU for positives, per-BLOCK partials (no atomics) ----------------
__global__ __launch_bounds__(256) void dl_pass2(
    const float4* __restrict__ bbox, const float* __restrict__ conf,
    const float4* __restrict__ gt,
    const float* __restrict__ posflag, const uint8_t* __restrict__ best_idx,
    uint32_t* __restrict__ negkey,
    float* __restrict__ part_loc, float* __restrict__ part_fl, float* __restrict__ part_np) {
  const int img = blockIdx.y;
  const int bx = blockIdx.x;
  const int a = bx * 256 + threadIdx.x;
  const int idx = img * A_N + a;

  const bool pos = posflag[idx] > 0.5f;

  const float l = conf[idx];
  const float tt = pos ? 1.0f : 0.0f;
  float ce = fmaxf(l, 0.0f) - l * tt + log1pf(expf(-fabsf(l)));
  float pp = 1.0f / (1.0f + expf(-l));
  float pt = pp * tt + (1.0f - pp) * (1.0f - tt);
  pt = fminf(fmaxf(pt, FEPS), 1.0f - FEPS);
  float om = 1.0f - pt;
  float fl = (pos ? 0.25f : 0.75f) * om * om * ce;

  negkey[idx] = pos ? 0u : __float_as_uint(fl);  // fl > 0 strictly; 0 sentinel sorts below all negatives

  float locv = 0.0f;
  if (pos) {
    float4 p = bbox[idx];
    float4 q = gt[img * G_N + best_idx[idx]];
    float ap = (p.z - p.x) * (p.w - p.y);
    float ag = (q.z - q.x) * (q.w - q.y);
    float ix1 = fmaxf(p.x, q.x), iy1 = fmaxf(p.y, q.y);
    float ix2 = fminf(p.z, q.z), iy2 = fminf(p.w, q.w);
    float iw = fmaxf(ix2 - ix1, 0.0f), ih = fmaxf(iy2 - iy1, 0.0f);
    float inter = iw * ih;
    float iou = inter / (ap + ag - inter + FEPS);
    float cpx = (p.x + p.z) * 0.5f, cpy = (p.y + p.w) * 0.5f;
    float cgx = (q.x + q.z) * 0.5f, cgy = (q.y + q.w) * 0.5f;
    float dx = cpx - cgx, dy = cpy - cgy;
    float cd2 = dx * dx + dy * dy;
    float ex1 = fminf(p.x, q.x), ey1 = fminf(p.y, q.y);
    float ex2 = fmaxf(p.z, q.z), ey2 = fmaxf(p.w, q.w);
    float ddx = ex2 - ex1, ddy = ey2 - ey1;
    float dg2 = ddx * ddx + ddy * ddy + FEPS;
    locv = 1.0f - iou + cd2 / dg2;  // LOC_LOSS_WEIGHT = 1
  }

  float flp = pos ? fl : 0.0f;
  float np1 = pos ? 1.0f : 0.0f;
  for (int o = 32; o; o >>= 1) {
    locv += __shfl_down(locv, o);
    flp  += __shfl_down(flp, o);
    np1  += __shfl_down(np1, o);
  }
  __shared__ float sl[4], sf[4], sn[4];
  if ((threadIdx.x & 63) == 0) {
    int w = threadIdx.x >> 6;
    sl[w] = locv; sf[w] = flp; sn[w] = np1;
  }
  __syncthreads();
  if (threadIdx.x == 0) {
    const int pi = img * 256 + bx;
    part_loc[pi] = sl[0] + sl[1] + sl[2] + sl[3];
    part_fl[pi]  = sf[0] + sf[1] + sf[2] + sf[3];
    part_np[pi]  = sn[0] + sn[1] + sn[2] + sn[3];  // integer-valued, exact
  }
}

// ---------------- K4: reduce partials + exact top-k via histogram + boundary-bin select ----------------
#define NBIN 4096
#define SHB  19      // bin = keybits >> 19
#define CAP  6144

__global__ __launch_bounds__(1024) void dl_select(
    const uint32_t* __restrict__ negkey,
    const float* __restrict__ part_loc, const float* __restrict__ part_fl,
    const float* __restrict__ part_np, float* __restrict__ acc) {
  const int img = blockIdx.x;
  const int t = threadIdx.x;
  const uint4* __restrict__ k4 = (const uint4*)(negkey + (size_t)img * A_N);
  const int N4 = A_N / 4;  // 16384

  __shared__ uint32_t cnt[NBIN];
  __shared__ float    bsum[NBIN];
  __shared__ uint32_t cbuf[CAP];
  __shared__ float s3[3][4];
  __shared__ float redf[16];
  __shared__ int   redi[16];
  __shared__ float np_sh, psum_sh, loc_sh, sstar_sh, negsum_sh;
  __shared__ uint32_t bstar_sh, cstar_sh, ccnt_sh;

  for (int i = t; i < NBIN; i += 1024) { cnt[i] = 0u; bsum[i] = 0.f; }

  // ---- prologue: reduce the 256 per-block partials of this image ----
  float lv = 0.f, fv = 0.f, nv = 0.f;
  if (t < 256) {
    lv = part_loc[img * 256 + t];
    fv = part_fl[img * 256 + t];
    nv = part_np[img * 256 + t];
  }
  for (int o = 32; o; o >>= 1) {
    lv += __shfl_down(lv, o);
    fv += __shfl_down(fv, o);
    nv += __shfl_down(nv, o);
  }
  if (t < 256 && (t & 63) == 0) { s3[0][t >> 6] = lv; s3[1][t >> 6] = fv; s3[2][t >> 6] = nv; }
  __syncthreads();
  if (t == 0) {
    loc_sh  = s3[0][0] + s3[0][1] + s3[0][2] + s3[0][3];
    psum_sh = s3[1][0] + s3[1][1] + s3[1][2] + s3[1][3];
    np_sh   = s3[2][0] + s3[2][1] + s3[2][2] + s3[2][3];
    negsum_sh = 0.f;
  }
  __syncthreads();

  const int np = (int)(np_sh + 0.5f);
  const int k = min(A_N - np, 3 * np);

  if (k > 0) {
    // ---- one full pass: per-bin count + sum ----
    for (int i = t; i < N4; i += 1024) {
      uint4 v = k4[i];
      atomicAdd(&cnt[v.x >> SHB], 1u); atomicAdd(&bsum[v.x >> SHB], __uint_as_float(v.x));
      atomicAdd(&cnt[v.y >> SHB], 1u); atomicAdd(&bsum[v.y >> SHB], __uint_as_float(v.y));
      atomicAdd(&cnt[v.z >> SHB], 1u); atomicAdd(&bsum[v.z >> SHB], __uint_as_float(v.z));
      atomicAdd(&cnt[v.w >> SHB], 1u); atomicAdd(&bsum[v.w >> SHB], __uint_as_float(v.w));
    }
    __syncthreads();

    // ---- wave 0: find threshold bin b*: C(b*) < k <= C(b*)+cnt[b*] ----
    if (t < 64) {
      const int CH = NBIN / 64;
      const int lob = NBIN - CH * (t + 1);   // lane 0 owns the TOP chunk
      uint32_t csum = 0;
      for (int b = lob; b < lob + CH; ++b) csum += cnt[b];
      uint32_t pre = csum;
      for (int o = 1; o < 64; o <<= 1) { uint32_t u = __shfl_up(pre, o); if (t >= o) pre += u; }
      uint32_t run = pre - csum;             // keys in bins above my chunk
      for (int b = lob + CH - 1; b >= lob; --b) {
        uint32_t c = cnt[b];
        if (run < (uint32_t)k && run + c >= (uint32_t)k) { bstar_sh = (uint32_t)b; cstar_sh = run; }
        run += c;
      }
    }
    __syncthreads();
    const int bstar = (int)bstar_sh;
    const uint32_t cstar = cstar_sh;
    const uint32_t cbin = cnt[bstar];
    const uint32_t r = (uint32_t)k - cstar;  // 1 <= r <= cbin

    // ---- Sstar = sum of all keys in bins > b* ----
    float s = 0.f;
    for (int i = t; i < NBIN; i += 1024) if (i > bstar) s += bsum[i];
    for (int o = 32; o; o >>= 1) s += __shfl_down(s, o);
    if ((t & 63) == 0) redf[t >> 6] = s;
    __syncthreads();
    if (t == 0) {
      float ss = 0.f;
      #pragma unroll
      for (int w = 0; w < 16; ++w) ss += redf[w];
      sstar_sh = ss;
    }
    __syncthreads();

    if (r == cbin) {
      if (t == 0) negsum_sh = sstar_sh + bsum[bstar];
    } else if (cbin <= (uint32_t)CAP) {
      // ---- compact boundary bin to LDS, then in-LDS bisect (19 bits) ----
      if (t == 0) ccnt_sh = 0u;
      __syncthreads();
      for (int i = t; i < N4; i += 1024) {
        uint4 v = k4[i];
        if ((v.x >> SHB) == (uint32_t)bstar) cbuf[atomicAdd(&ccnt_sh, 1u)] = v.x;
        if ((v.y >> SHB) == (uint32_t)bstar) cbuf[atomicAdd(&ccnt_sh, 1u)] = v.y;
        if ((v.z >> SHB) == (uint32_t)bstar) cbuf[atomicAdd(&ccnt_sh, 1u)] = v.z;
        if ((v.w >> SHB) == (uint32_t)bstar) cbuf[atomicAdd(&ccnt_sh, 1u)] = v.w;
      }
      __syncthreads();
      if (t < 64) {
        const int n = (int)ccnt_sh;
        uint32_t lo = (uint32_t)bstar << SHB;
        uint32_t hi = ((uint32_t)bstar + 1u) << SHB;
        while (hi - lo > 1u) {
          uint32_t mid = lo + ((hi - lo) >> 1);
          int c = 0;
          for (int i = t; i < n; i += 64) c += (cbuf[i] >= mid) ? 1 : 0;
          for (int o = 32; o; o >>= 1) c += __shfl_down(c, o);
          c = __shfl(c, 0);
          if ((uint32_t)c >= r) lo = mid; else hi = mid;
        }
        float s2 = 0.f; int cg = 0;
        for (int i = t; i < n; i += 64) {
          uint32_t x = cbuf[i];
          if (x > lo) { s2 += __uint_as_float(x); cg++; }
        }
        for (int o = 32; o; o >>= 1) { s2 += __shfl_down(s2, o); cg += __shfl_down(cg, o); }
        if (t == 0) negsum_sh = sstar_sh + s2 + (float)(int)(r - (uint32_t)cg) * __uint_as_float(lo);
      }
    } else {
      // ---- fallback (huge tie bin): global bisection restricted to the bin's 19-bit range ----
      uint32_t lo = (uint32_t)bstar << SHB;
      uint32_t hi = ((uint32_t)bstar + 1u) << SHB;
      while (hi - lo > 1u) {
        uint32_t mid = lo + ((hi - lo) >> 1);
        int c = 0;
        for (int i = t; i < N4; i += 1024) {
          uint4 v = k4[i];
          c += (v.x >= mid) + (v.y >= mid) + (v.z >= mid) + (v.w >= mid);
        }
        for (int o = 32; o; o >>= 1) c += __shfl_down(c, o);
        if ((t & 63) == 0) redi[t >> 6] = c;
        __syncthreads();
        c = 0;
        #pragma unroll
        for (int w = 0; w < 16; ++w) c += redi[w];
        __syncthreads();
        if (c >= k) lo = mid; else hi = mid;
      }
      float s2 = 0.f; int cg = 0;
      for (int i = t; i < N4; i += 1024) {
        uint4 v = k4[i];
        if (v.x > lo) { s2 += __uint_as_float(v.x); cg++; }
        if (v.y > lo) { s2 += __uint_as_float(v.y); cg++; }
        if (v.z > lo) { s2 += __uint_as_float(v.z); cg++; }
        if (v.w > lo) { s2 += __uint_as_float(v.w); cg++; }
      }
      for (int o = 32; o; o >>= 1) { s2 += __shfl_down(s2, o); cg += __shfl_down(cg, o); }
      if ((t & 63) == 0) { redf[t >> 6] = s2; redi[t >> 6] = cg; }
      __syncthreads();
      if (t == 0) {
        float ss = 0.f; int cc = 0;
        #pragma unroll
        for (int w = 0; w < 16; ++w) { ss += redf[w]; cc += redi[w]; }
        negsum_sh = ss + (float)(k - cc) * __uint_as_float(lo);
      }
    }
  }
  __syncthreads();
  if (t == 0) {
    acc[img] = loc_sh;
    acc[32 + img] = (float)np;
    acc[48 + img] = (psum_sh + negsum_sh) / fmaxf((float)(np + k), 1.0f);
  }
}

// ---------------- K5: final combine ----------------
__global__ void dl_final(const float* __restrict__ acc, float* __restrict__ out) {
  if (threadIdx.x == 0 && blockIdx.x == 0) {
    float sl = 0.0f, sc = 0.0f, sn = 0.0f;
    for (int i = 0; i < B_N; ++i) {
      sl += acc[i];
      sc += acc[48 + i];
      sn += acc[32 + i];
    }
    float tp = fmaxf(sn, 1.0f);
    float al = sl / tp;
    float ac = sc / tp;
    out[0] = al + ac;
    out[1] = ac;
    out[2] = al;
  }
}

extern "C" void kernel_launch(void* const* d_in, const int* in_sizes, int n_in,
                              void* d_out, int out_size, void* d_ws, size_t ws_size,
                              hipStream_t stream) {
  (void)in_sizes; (void)n_in; (void)out_size; (void)ws_size;

  const float4* bbox = (const float4*)d_in[0];   // [B, A, 4] f32
  const float*  conf = (const float*)d_in[1];    // [B, A] f32
  const float4* gt   = (const float4*)d_in[2];   // [B, G, 4] f32
  float* out = (float*)d_out;

  char* ws = (char*)d_ws;
  const size_t SZ = (size_t)B_N * A_N * 4;                 // 4 MiB
  float*              posflag  = (float*)(ws);             // 4 MiB
  uint32_t*           negkey   = (uint32_t*)(ws + SZ);     // 4 MiB
  unsigned long long* gt_part  = (unsigned long long*)(ws + 2 * SZ);          // 2 MiB [16][256][64]
  uint8_t*            best_idx = (uint8_t*)(ws + 2 * SZ + (size_t)B_N * 256 * G_N * 8);  // 1 MiB
  char* tail = ws + 2 * SZ + (size_t)B_N * 256 * G_N * 8 + (size_t)B_N * A_N;
  float* part_loc = (float*)(tail);                        // 16 KiB
  float* part_fl  = (float*)(tail + 16384);
  float* part_np  = (float*)(tail + 32768);
  float* acc      = (float*)(tail + 49152);                // 64 floats

  dl_pass1<<<dim3(A_N / 256, B_N), 256, 0, stream>>>(bbox, gt, posflag, best_idx, gt_part);
  dl_force<<<B_N * G_N, 64, 0, stream>>>(gt_part, posflag);
  dl_pass2<<<dim3(A_N / 256, B_N), 256, 0, stream>>>(bbox, conf, gt, posflag, best_idx,
                                                     negkey, part_loc, part_fl, part_np);
  dl_select<<<B_N, 1024, 0, stream>>>(negkey, part_loc, part_fl, part_np, acc);
  dl_final<<<1, 64, 0, stream>>>(acc, out);
}

// Round 4
// 199.132 us; speedup vs baseline: 1.3098x; 1.3098x over previous
//
#include <hip/hip_runtime.h>
#include <stdint.h>

#define A_N 65536
#define B_N 16
#define G_N 64
#define FEPS 1e-7f

#define NBIN 2048
#define SHB  21      // bin = keybits >> 21  (sign + 8 exp + 2 mantissa bits)
#define CAP  6144

// ---------------- K1: per-anchor best gt (row argmax, cross-mult) + per-(block,gt) best anchor
// (column argmax, lane-owns-gt) — no division, no atomics in the hot loops ----------------
__global__ __launch_bounds__(256) void dl_pass1(
    const float4* __restrict__ bbox, const float4* __restrict__ gt,
    float* __restrict__ posflag, uint8_t* __restrict__ best_idx,
    unsigned long long* __restrict__ gt_part, uint32_t* __restrict__ hist_zero) {
  const int img = blockIdx.y;
  const int bx  = blockIdx.x;
  const int t   = threadIdx.x;
  const int wave = t >> 6, lane = t & 63;
  const int a = bx * 256 + t;

  // zero the global histogram (cnt+sum, 65536 words total across 4096 blocks)
  if (t < 16) hist_zero[(size_t)(img * 256 + bx) * 16 + t] = 0u;

  __shared__ float4 sg[G_N];
  __shared__ float  sga[G_N];
  __shared__ float4 sa[256];
  __shared__ float  saa[256];
  __shared__ unsigned long long spart[4][G_N];

  float4 p = bbox[img * A_N + a];
  float pa = __fmul_rn(__fsub_rn(p.z, p.x), __fsub_rn(p.w, p.y));
  sa[t] = p; saa[t] = pa;
  if (t < G_N) {
    float4 q0 = gt[img * G_N + t];
    sg[t] = q0;
    sga[t] = __fmul_rn(__fsub_rn(q0.z, q0.x), __fsub_rn(q0.w, q0.y));
  }
  __syncthreads();

  // ---- phase A: row pass (each lane = its anchor, loop over gts) ----
  // argmax by cross-multiplication: inter/den > bi/bd  <=>  inter*bd > bi*den (all positive)
  // pos threshold EXACT: iou > 0.5 <=> sign(2*inter - den) > 0 (RN rounding preserves sign)
  float bi = 0.f, bd = 1.f; int bidx = 0; float posm = -1.f;
  #pragma unroll 4
  for (int g = 0; g < G_N; ++g) {
    float4 q = sg[g];
    float ix1 = fmaxf(p.x, q.x), iy1 = fmaxf(p.y, q.y);
    float ix2 = fminf(p.z, q.z), iy2 = fminf(p.w, q.w);
    float iw = fmaxf(__fsub_rn(ix2, ix1), 0.f);
    float ih = fmaxf(__fsub_rn(iy2, iy1), 0.f);
    float inter = __fmul_rn(iw, ih);
    float den = __fadd_rn(__fsub_rn(__fadd_rn(pa, sga[g]), inter), FEPS);  // exact numpy den
    if (inter * bd > bi * den) { bi = inter; bd = den; bidx = g; }  // strict > keeps first occurrence
    posm = fmaxf(posm, __fmaf_rn(2.f, inter, -den));
  }
  posflag[img * A_N + a] = (posm > 0.f) ? 1.f : 0.f;
  best_idx[img * A_N + a] = (uint8_t)bidx;

  // ---- phase B: column pass (each lane owns gt=lane, loop over this wave's 64 anchors) ----
  float4 q = sg[lane];
  float qa = sga[lane];
  float ci = 0.f, cd = 1.f; int caidx = 0;
  const int base = wave * 64;
  #pragma unroll 4
  for (int j = 0; j < 64; ++j) {
    float4 ap = sa[base + j];          // uniform address within wave -> LDS broadcast
    float aa = saa[base + j];
    float ix1 = fmaxf(ap.x, q.x), iy1 = fmaxf(ap.y, q.y);
    float ix2 = fminf(ap.z, q.z), iy2 = fminf(ap.w, q.w);
    float iw = fmaxf(__fsub_rn(ix2, ix1), 0.f);
    float ih = fmaxf(__fsub_rn(iy2, iy1), 0.f);
    float inter = __fmul_rn(iw, ih);
    float den = __fadd_rn(__fsub_rn(__fadd_rn(aa, qa), inter), FEPS);
    if (inter * cd > ci * den) { ci = inter; cd = den; caidx = base + j; }
  }
  // comparable scalar key: approx ratio bits (1-ulp rcp; flips only exact near-ties)
  float ratio = ci * __builtin_amdgcn_rcpf(cd);
  unsigned long long key = ((unsigned long long)__float_as_uint(ratio) << 32)
                         | (unsigned)~(unsigned)(bx * 256 + caidx);  // smaller global idx wins ties
  spart[wave][lane] = key;
  __syncthreads();
  if (t < G_N) {
    unsigned long long m = spart[0][t];
    if (spart[1][t] > m) m = spart[1][t];
    if (spart[2][t] > m) m = spart[2][t];
    if (spart[3][t] > m) m = spart[3][t];
    gt_part[(((size_t)(img << 8) | bx) << 6) | t] = m;  // coalesced 512B store
  }
}

// ---------------- K2: reduce per-block gt keys, force best anchor per GT positive ----------------
__global__ __launch_bounds__(64) void dl_force(const unsigned long long* __restrict__ gt_part,
                                               float* __restrict__ posflag) {
  const int p = blockIdx.x;          // 0..1023 = (img, g)
  const int img = p >> 6, g = p & 63;
  const int t = threadIdx.x;
  unsigned long long m = 0ull;
  #pragma unroll
  for (int j = 0; j < 4; ++j) {
    unsigned long long v = gt_part[(((size_t)(img << 8) | (t + j * 64)) << 6) | g];
    if (v > m) m = v;
  }
  for (int o = 32; o; o >>= 1) {
    unsigned long long other = __shfl_down(m, o);
    if (other > m) m = other;
  }
  if (t == 0) {
    // all-zero column: every partial has ratio bits 0, max low-word = ~0 -> anchor 0 (numpy argmax)
    uint32_t a = ~(uint32_t)(m & 0xFFFFFFFFull);
    posflag[(size_t)img * A_N + a] = 2.0f;  // > 0.5 => positive; best_idx untouched
  }
}

// ---------------- K3: focal, DIoU, per-block partials + hierarchical histogram ----------------
__global__ __launch_bounds__(256) void dl_pass2(
    const float4* __restrict__ bbox, const float* __restrict__ conf,
    const float4* __restrict__ gt,
    const float* __restrict__ posflag, const uint8_t* __restrict__ best_idx,
    uint32_t* __restrict__ negkey,
    uint32_t* __restrict__ hist_cnt, float* __restrict__ hist_sum,
    float* __restrict__ part_loc, float* __restrict__ part_fl, float* __restrict__ part_np) {
  const int img = blockIdx.y;
  const int bx = blockIdx.x;
  const int a = bx * 256 + threadIdx.x;
  const int idx = img * A_N + a;

  __shared__ uint32_t hc[NBIN];
  __shared__ float    hs[NBIN];
  for (int i = threadIdx.x; i < NBIN; i += 256) { hc[i] = 0u; hs[i] = 0.f; }

  const bool pos = posflag[idx] > 0.5f;

  const float l = conf[idx];
  const float tt = pos ? 1.0f : 0.0f;
  float ce = fmaxf(l, 0.0f) - l * tt + log1pf(expf(-fabsf(l)));
  float pp = 1.0f / (1.0f + expf(-l));
  float pt = pp * tt + (1.0f - pp) * (1.0f - tt);
  pt = fminf(fmaxf(pt, FEPS), 1.0f - FEPS);
  float om = 1.0f - pt;
  float fl = (pos ? 0.25f : 0.75f) * om * om * ce;

  negkey[idx] = pos ? 0u : __float_as_uint(fl);  // fl > 0 strictly; 0 sentinel below all negatives

  float locv = 0.0f;
  if (pos) {
    float4 p = bbox[idx];
    float4 q = gt[img * G_N + best_idx[idx]];
    float ap = (p.z - p.x) * (p.w - p.y);
    float ag = (q.z - q.x) * (q.w - q.y);
    float ix1 = fmaxf(p.x, q.x), iy1 = fmaxf(p.y, q.y);
    float ix2 = fminf(p.z, q.z), iy2 = fminf(p.w, q.w);
    float iw = fmaxf(ix2 - ix1, 0.0f), ih = fmaxf(iy2 - iy1, 0.0f);
    float inter = iw * ih;
    float iou = inter / (ap + ag - inter + FEPS);
    float cpx = (p.x + p.z) * 0.5f, cpy = (p.y + p.w) * 0.5f;
    float cgx = (q.x + q.z) * 0.5f, cgy = (q.y + q.w) * 0.5f;
    float dx = cpx - cgx, dy = cpy - cgy;
    float cd2 = dx * dx + dy * dy;
    float ex1 = fminf(p.x, q.x), ey1 = fminf(p.y, q.y);
    float ex2 = fmaxf(p.z, q.z), ey2 = fmaxf(p.w, q.w);
    float ddx = ex2 - ex1, ddy = ey2 - ey1;
    float dg2 = ddx * ddx + ddy * ddy + FEPS;
    locv = 1.0f - iou + cd2 / dg2;  // LOC_LOSS_WEIGHT = 1
  }

  __syncthreads();  // hc/hs zeroed before use
  if (!pos) {
    uint32_t kb = __float_as_uint(fl);
    atomicAdd(&hc[kb >> SHB], 1u);       // 256 keys into 2048 bins: ~conflict-free
    atomicAdd(&hs[kb >> SHB], fl);
  }

  float flp = pos ? fl : 0.0f;
  float np1 = pos ? 1.0f : 0.0f;
  for (int o = 32; o; o >>= 1) {
    locv += __shfl_down(locv, o);
    flp  += __shfl_down(flp, o);
    np1  += __shfl_down(np1, o);
  }
  __shared__ float sl[4], sf[4], sn[4];
  if ((threadIdx.x & 63) == 0) {
    int w = threadIdx.x >> 6;
    sl[w] = locv; sf[w] = flp; sn[w] = np1;
  }
  __syncthreads();
  // flush nonzero bins: <=256 global atomics per block, max depth 256 per address
  for (int i = threadIdx.x; i < NBIN; i += 256) {
    uint32_t c = hc[i];
    if (c) {
      atomicAdd(&hist_cnt[img * NBIN + i], c);
      atomicAdd(&hist_sum[img * NBIN + i], hs[i]);
    }
  }
  if (threadIdx.x == 0) {
    const int pi = img * 256 + bx;
    part_loc[pi] = sl[0] + sl[1] + sl[2] + sl[3];
    part_fl[pi]  = sf[0] + sf[1] + sf[2] + sf[3];
    part_np[pi]  = sn[0] + sn[1] + sn[2] + sn[3];  // integer-valued, exact
  }
}

// ---------------- K4: read hist, threshold bin, compact boundary bin, exact k-th ----------------
__global__ __launch_bounds__(1024) void dl_select(
    const uint32_t* __restrict__ negkey,
    const uint32_t* __restrict__ hist_cnt, const float* __restrict__ hist_sum,
    const float* __restrict__ part_loc, const float* __restrict__ part_fl,
    const float* __restrict__ part_np, float* __restrict__ acc) {
  const int img = blockIdx.x;
  const int t = threadIdx.x;
  const uint4* __restrict__ k4 = (const uint4*)(negkey + (size_t)img * A_N);
  const int N4 = A_N / 4;  // 16384

  __shared__ uint32_t cnt[NBIN];
  __shared__ float    bsum[NBIN];
  __shared__ uint32_t cbuf[CAP];
  __shared__ float s3[3][4];
  __shared__ float redf[16];
  __shared__ int   redi[16];
  __shared__ float np_sh, psum_sh, loc_sh, sstar_sh, negsum_sh;
  __shared__ uint32_t bstar_sh, cstar_sh, ccnt_sh;

  for (int i = t; i < NBIN; i += 1024) {
    cnt[i]  = hist_cnt[img * NBIN + i];
    bsum[i] = hist_sum[img * NBIN + i];
  }

  // ---- prologue: reduce the 256 per-block partials of this image ----
  float lv = 0.f, fv = 0.f, nv = 0.f;
  if (t < 256) {
    lv = part_loc[img * 256 + t];
    fv = part_fl[img * 256 + t];
    nv = part_np[img * 256 + t];
  }
  for (int o = 32; o; o >>= 1) {
    lv += __shfl_down(lv, o);
    fv += __shfl_down(fv, o);
    nv += __shfl_down(nv, o);
  }
  if (t < 256 && (t & 63) == 0) { s3[0][t >> 6] = lv; s3[1][t >> 6] = fv; s3[2][t >> 6] = nv; }
  __syncthreads();
  if (t == 0) {
    loc_sh  = s3[0][0] + s3[0][1] + s3[0][2] + s3[0][3];
    psum_sh = s3[1][0] + s3[1][1] + s3[1][2] + s3[1][3];
    np_sh   = s3[2][0] + s3[2][1] + s3[2][2] + s3[2][3];
    negsum_sh = 0.f;
  }
  __syncthreads();

  const int np = (int)(np_sh + 0.5f);
  const int k = min(A_N - np, 3 * np);

  if (k > 0) {
    // ---- wave 0: find threshold bin b*: C(b*) < k <= C(b*)+cnt[b*] ----
    if (t < 64) {
      const int CH = NBIN / 64;              // 32
      const int lob = NBIN - CH * (t + 1);   // lane 0 owns the TOP chunk
      uint32_t csum = 0;
      for (int b = lob; b < lob + CH; ++b) csum += cnt[b];
      uint32_t pre = csum;
      for (int o = 1; o < 64; o <<= 1) { uint32_t u = __shfl_up(pre, o); if (t >= o) pre += u; }
      uint32_t run = pre - csum;             // keys in bins above my chunk
      for (int b = lob + CH - 1; b >= lob; --b) {
        uint32_t c = cnt[b];
        if (run < (uint32_t)k && run + c >= (uint32_t)k) { bstar_sh = (uint32_t)b; cstar_sh = run; }
        run += c;
      }
    }
    __syncthreads();
    const int bstar = (int)bstar_sh;
    const uint32_t cstar = cstar_sh;
    const uint32_t cbin = cnt[bstar];
    const uint32_t r = (uint32_t)k - cstar;  // 1 <= r <= cbin

    // ---- Sstar = sum of all keys in bins > b* ----
    float s = 0.f;
    for (int i = t; i < NBIN; i += 1024) if (i > bstar) s += bsum[i];
    for (int o = 32; o; o >>= 1) s += __shfl_down(s, o);
    if ((t & 63) == 0) redf[t >> 6] = s;
    __syncthreads();
    if (t == 0) {
      float ss = 0.f;
      #pragma unroll
      for (int w = 0; w < 16; ++w) ss += redf[w];
      sstar_sh = ss;
    }
    __syncthreads();

    if (r == cbin) {
      if (t == 0) negsum_sh = sstar_sh + bsum[bstar];
    } else if (cbin <= (uint32_t)CAP) {
      // ---- compact boundary bin (typically ~50-300 keys), then wave-0 bisect 21 bits ----
      if (t == 0) ccnt_sh = 0u;
      __syncthreads();
      for (int i = t; i < N4; i += 1024) {
        uint4 v = k4[i];
        if ((v.x >> SHB) == (uint32_t)bstar) cbuf[atomicAdd(&ccnt_sh, 1u)] = v.x;
        if ((v.y >> SHB) == (uint32_t)bstar) cbuf[atomicAdd(&ccnt_sh, 1u)] = v.y;
        if ((v.z >> SHB) == (uint32_t)bstar) cbuf[atomicAdd(&ccnt_sh, 1u)] = v.z;
        if ((v.w >> SHB) == (uint32_t)bstar) cbuf[atomicAdd(&ccnt_sh, 1u)] = v.w;
      }
      __syncthreads();
      if (t < 64) {
        const int n = (int)ccnt_sh;
        uint32_t lo = (uint32_t)bstar << SHB;
        uint32_t hi = ((uint32_t)bstar + 1u) << SHB;
        while (hi - lo > 1u) {
          uint32_t mid = lo + ((hi - lo) >> 1);
          int c = 0;
          for (int i = t; i < n; i += 64) c += (cbuf[i] >= mid) ? 1 : 0;
          for (int o = 32; o; o >>= 1) c += __shfl_down(c, o);
          c = __shfl(c, 0);
          if ((uint32_t)c >= r) lo = mid; else hi = mid;
        }
        float s2 = 0.f; int cg = 0;
        for (int i = t; i < n; i += 64) {
          uint32_t x = cbuf[i];
          if (x > lo) { s2 += __uint_as_float(x); cg++; }
        }
        for (int o = 32; o; o >>= 1) { s2 += __shfl_down(s2, o); cg += __shfl_down(cg, o); }
        if (t == 0) negsum_sh = sstar_sh + s2 + (float)(int)(r - (uint32_t)cg) * __uint_as_float(lo);
      }
    } else {
      // ---- fallback (pathological tie bin): global bisection within the bin's range ----
      uint32_t lo = (uint32_t)bstar << SHB;
      uint32_t hi = ((uint32_t)bstar + 1u) << SHB;
      while (hi - lo > 1u) {
        uint32_t mid = lo + ((hi - lo) >> 1);
        int c = 0;
        for (int i = t; i < N4; i += 1024) {
          uint4 v = k4[i];
          c += (v.x >= mid) + (v.y >= mid) + (v.z >= mid) + (v.w >= mid);
        }
        for (int o = 32; o; o >>= 1) c += __shfl_down(c, o);
        if ((t & 63) == 0) redi[t >> 6] = c;
        __syncthreads();
        c = 0;
        #pragma unroll
        for (int w = 0; w < 16; ++w) c += redi[w];
        __syncthreads();
        if (c >= k) lo = mid; else hi = mid;
      }
      float s2 = 0.f; int cg = 0;
      for (int i = t; i < N4; i += 1024) {
        uint4 v = k4[i];
        if (v.x > lo) { s2 += __uint_as_float(v.x); cg++; }
        if (v.y > lo) { s2 += __uint_as_float(v.y); cg++; }
        if (v.z > lo) { s2 += __uint_as_float(v.z); cg++; }
        if (v.w > lo) { s2 += __uint_as_float(v.w); cg++; }
      }
      for (int o = 32; o; o >>= 1) { s2 += __shfl_down(s2, o); cg += __shfl_down(cg, o); }
      if ((t & 63) == 0) { redf[t >> 6] = s2; redi[t >> 6] = cg; }
      __syncthreads();
      if (t == 0) {
        float ss = 0.f; int cc = 0;
        #pragma unroll
        for (int w = 0; w < 16; ++w) { ss += redf[w]; cc += redi[w]; }
        negsum_sh = ss + (float)(k - cc) * __uint_as_float(lo);
      }
    }
  }
  __syncthreads();
  if (t == 0) {
    acc[img] = loc_sh;
    acc[32 + img] = (float)np;
    acc[48 + img] = (psum_sh + negsum_sh) / fmaxf((float)(np + k), 1.0f);
  }
}

// ---------------- K5: final combine ----------------
__global__ void dl_final(const float* __restrict__ acc, float* __restrict__ out) {
  if (threadIdx.x == 0 && blockIdx.x == 0) {
    float sl = 0.0f, sc = 0.0f, sn = 0.0f;
    for (int i = 0; i < B_N; ++i) {
      sl += acc[i];
      sc += acc[48 + i];
      sn += acc[32 + i];
    }
    float tp = fmaxf(sn, 1.0f);
    float al = sl / tp;
    float ac = sc / tp;
    out[0] = al + ac;
    out[1] = ac;
    out[2] = al;
  }
}

extern "C" void kernel_launch(void* const* d_in, const int* in_sizes, int n_in,
                              void* d_out, int out_size, void* d_ws, size_t ws_size,
                              hipStream_t stream) {
  (void)in_sizes; (void)n_in; (void)out_size; (void)ws_size;

  const float4* bbox = (const float4*)d_in[0];   // [B, A, 4] f32
  const float*  conf = (const float*)d_in[1];    // [B, A] f32
  const float4* gt   = (const float4*)d_in[2];   // [B, G, 4] f32
  float* out = (float*)d_out;

  char* ws = (char*)d_ws;
  const size_t SZ = (size_t)B_N * A_N * 4;                 // 4 MiB
  float*              posflag  = (float*)(ws);             // 4 MiB
  uint32_t*           negkey   = (uint32_t*)(ws + SZ);     // 4 MiB
  unsigned long long* gt_part  = (unsigned long long*)(ws + 2 * SZ);          // 2 MiB
  uint8_t*            best_idx = (uint8_t*)(ws + 2 * SZ + (size_t)B_N * 256 * G_N * 8);  // 1 MiB
  char* hb = ws + 2 * SZ + (size_t)B_N * 256 * G_N * 8 + (size_t)B_N * A_N;
  uint32_t* hist_cnt = (uint32_t*)(hb);                    // 128 KiB  [16][2048]
  float*    hist_sum = (float*)(hb + (size_t)B_N * NBIN * 4);  // 128 KiB
  char* tail = hb + 2 * (size_t)B_N * NBIN * 4;
  float* part_loc = (float*)(tail);                        // 16 KiB
  float* part_fl  = (float*)(tail + 16384);
  float* part_np  = (float*)(tail + 32768);
  float* acc      = (float*)(tail + 49152);                // 64 floats

  dl_pass1<<<dim3(A_N / 256, B_N), 256, 0, stream>>>(bbox, gt, posflag, best_idx, gt_part,
                                                     hist_cnt /* zeroes cnt+sum, contiguous */);
  dl_force<<<B_N * G_N, 64, 0, stream>>>(gt_part, posflag);
  dl_pass2<<<dim3(A_N / 256, B_N), 256, 0, stream>>>(bbox, conf, gt, posflag, best_idx,
                                                     negkey, hist_cnt, hist_sum,
                                                     part_loc, part_fl, part_np);
  dl_select<<<B_N, 1024, 0, stream>>>(negkey, hist_cnt, hist_sum,
                                      part_loc, part_fl, part_np, acc);
  dl_final<<<1, 64, 0, stream>>>(acc, out);
}

// Round 5
// 183.398 us; speedup vs baseline: 1.4222x; 1.0858x over previous
//
#include <hip/hip_runtime.h>
#include <stdint.h>

#define A_N 65536
#define B_N 16
#define G_N 64
#define FEPS 1e-7f

#define NBIN 2048
#define SHB  21      // bin = keybits >> 21  (sign + 8 exp + 2 mantissa bits)
#define CAP  6144

// ---------------- K1: single-loop row argmax + rotating-register column argmax ----------------
// Pairs iterated as (a=lane, g=(lane+j)&63). colkey rotates one lane per iteration so that
// at iteration j it holds the running column max for g=(lane+j); after 64 rotations lane l
// holds the wave-level column max for gt l. No second IoU pass, no anchor staging.
__global__ __launch_bounds__(256) void dl_pass1(
    const float4* __restrict__ bbox, const float4* __restrict__ gt,
    float* __restrict__ posflag, uint8_t* __restrict__ best_idx,
    unsigned long long* __restrict__ gt_part, uint32_t* __restrict__ hist_zero,
    uint32_t* __restrict__ done_ctr) {
  const int img = blockIdx.y;
  const int bx  = blockIdx.x;
  const int t   = threadIdx.x;
  const int wave = t >> 6, lane = t & 63;
  const int a = bx * 256 + t;

  // zero the global histogram (cnt+sum, 65536 words total across 4096 blocks)
  if (t < 16) hist_zero[(size_t)(img * 256 + bx) * 16 + t] = 0u;
  if (bx == 0 && img == 0 && t == 0) *done_ctr = 0u;  // for select's last-block finale

  __shared__ float4 sg[G_N];
  __shared__ float  sga[G_N];
  __shared__ unsigned long long spart[4][G_N];

  if (t < G_N) {
    float4 q0 = gt[img * G_N + t];
    sg[t] = q0;
    // exact f32, no contraction (matches numpy bit-for-bit)
    sga[t] = __fmul_rn(__fsub_rn(q0.z, q0.x), __fsub_rn(q0.w, q0.y));
  }
  __syncthreads();

  float4 p = bbox[img * A_N + a];
  float pa = __fmul_rn(__fsub_rn(p.z, p.x), __fsub_rn(p.w, p.y));

  float bi = 0.f, bd = 1.f; int bidx = 0; float posm = -1.f;
  uint32_t colkey = 0u;                       // rotating column-max register
  const int rotsrc = (lane + 1) & 63;         // pull from next lane after each iter
  const uint32_t lanecomp = 63u - (uint32_t)lane;  // smaller lane wins ties under max

  int g = lane;
  #pragma unroll 4
  for (int j = 0; j < G_N; ++j) {
    float4 q = sg[g];
    float qa = sga[g];
    float ix1 = fmaxf(p.x, q.x), iy1 = fmaxf(p.y, q.y);
    float ix2 = fminf(p.z, q.z), iy2 = fminf(p.w, q.w);
    float iw = fmaxf(__fsub_rn(ix2, ix1), 0.f);
    float ih = fmaxf(__fsub_rn(iy2, iy1), 0.f);
    float inter = __fmul_rn(iw, ih);
    float den = __fadd_rn(__fsub_rn(__fadd_rn(pa, qa), inter), FEPS);  // exact numpy den
    // row argmax via cross-mult (no division); strict > keeps first-occurrence semantics
    if (inter * bd > bi * den) { bi = inter; bd = den; bidx = g; }
    // pos threshold EXACT: iou > 0.5 <=> sign(2*inter - den) > 0 (RN preserves sign)
    posm = fmaxf(posm, __fmaf_rn(2.f, inter, -den));
    // column candidate: approx ratio (1-ulp rcp), top 26 bits | lane-complement
    float ratio = inter * __builtin_amdgcn_rcpf(den);
    uint32_t key = (__float_as_uint(ratio) & 0xFFFFFFC0u) | lanecomp;
    if (key > colkey) colkey = key;
    colkey = __shfl(colkey, rotsrc);          // register now belongs to g+1
    g = (g + 1) & 63;
  }

  posflag[img * A_N + a] = (posm > 0.f) ? 1.f : 0.f;
  best_idx[img * A_N + a] = (uint8_t)bidx;

  // lane l now holds the wave's column max for gt l; build cross-block comparable u64 key
  uint32_t winlane = 63u - (colkey & 63u);
  uint32_t ganchor = (uint32_t)(bx * 256 + wave * 64) + winlane;
  unsigned long long wkey = ((unsigned long long)(colkey & 0xFFFFFFC0u) << 32)
                          | (unsigned)~ganchor;  // smaller global idx wins ties
  spart[wave][lane] = wkey;
  __syncthreads();
  if (t < G_N) {
    unsigned long long m = spart[0][t];
    if (spart[1][t] > m) m = spart[1][t];
    if (spart[2][t] > m) m = spart[2][t];
    if (spart[3][t] > m) m = spart[3][t];
    gt_part[(((size_t)(img << 8) | bx) << 6) | t] = m;  // coalesced 512B store
  }
}

// ---------------- K2: reduce per-block gt keys, force best anchor per GT positive ----------------
__global__ __launch_bounds__(64) void dl_force(const unsigned long long* __restrict__ gt_part,
                                               float* __restrict__ posflag) {
  const int p = blockIdx.x;          // 0..1023 = (img, g)
  const int img = p >> 6, g = p & 63;
  const int t = threadIdx.x;
  unsigned long long m = 0ull;
  #pragma unroll
  for (int j = 0; j < 4; ++j) {
    unsigned long long v = gt_part[(((size_t)(img << 8) | (t + j * 64)) << 6) | g];
    if (v > m) m = v;
  }
  for (int o = 32; o; o >>= 1) {
    unsigned long long other = __shfl_down(m, o);
    if (other > m) m = other;
  }
  if (t == 0) {
    // all-zero column: ratio bits 0 for every anchor, max low-word = ~0 -> anchor 0 (numpy argmax)
    uint32_t a = ~(uint32_t)(m & 0xFFFFFFFFull);
    posflag[(size_t)img * A_N + a] = 2.0f;  // > 0.5 => positive; best_idx untouched
  }
}

// ---------------- K3: focal, DIoU, per-block partials + hierarchical histogram ----------------
__global__ __launch_bounds__(256) void dl_pass2(
    const float4* __restrict__ bbox, const float* __restrict__ conf,
    const float4* __restrict__ gt,
    const float* __restrict__ posflag, const uint8_t* __restrict__ best_idx,
    uint32_t* __restrict__ negkey,
    uint32_t* __restrict__ hist_cnt, float* __restrict__ hist_sum,
    float* __restrict__ part_loc, float* __restrict__ part_fl, float* __restrict__ part_np) {
  const int img = blockIdx.y;
  const int bx = blockIdx.x;
  const int a = bx * 256 + threadIdx.x;
  const int idx = img * A_N + a;

  __shared__ uint32_t hc[NBIN];
  __shared__ float    hs[NBIN];
  for (int i = threadIdx.x; i < NBIN; i += 256) { hc[i] = 0u; hs[i] = 0.f; }

  const bool pos = posflag[idx] > 0.5f;

  const float l = conf[idx];
  const float tt = pos ? 1.0f : 0.0f;
  float ce = fmaxf(l, 0.0f) - l * tt + log1pf(expf(-fabsf(l)));
  float pp = 1.0f / (1.0f + expf(-l));
  float pt = pp * tt + (1.0f - pp) * (1.0f - tt);
  pt = fminf(fmaxf(pt, FEPS), 1.0f - FEPS);
  float om = 1.0f - pt;
  float fl = (pos ? 0.25f : 0.75f) * om * om * ce;

  negkey[idx] = pos ? 0u : __float_as_uint(fl);  // fl > 0 strictly; 0 sentinel below all negatives

  float locv = 0.0f;
  if (pos) {
    float4 p = bbox[idx];
    float4 q = gt[img * G_N + best_idx[idx]];
    float ap = (p.z - p.x) * (p.w - p.y);
    float ag = (q.z - q.x) * (q.w - q.y);
    float ix1 = fmaxf(p.x, q.x), iy1 = fmaxf(p.y, q.y);
    float ix2 = fminf(p.z, q.z), iy2 = fminf(p.w, q.w);
    float iw = fmaxf(ix2 - ix1, 0.0f), ih = fmaxf(iy2 - iy1, 0.0f);
    float inter = iw * ih;
    float iou = inter / (ap + ag - inter + FEPS);
    float cpx = (p.x + p.z) * 0.5f, cpy = (p.y + p.w) * 0.5f;
    float cgx = (q.x + q.z) * 0.5f, cgy = (q.y + q.w) * 0.5f;
    float dx = cpx - cgx, dy = cpy - cgy;
    float cd2 = dx * dx + dy * dy;
    float ex1 = fminf(p.x, q.x), ey1 = fminf(p.y, q.y);
    float ex2 = fmaxf(p.z, q.z), ey2 = fmaxf(p.w, q.w);
    float ddx = ex2 - ex1, ddy = ey2 - ey1;
    float dg2 = ddx * ddx + ddy * ddy + FEPS;
    locv = 1.0f - iou + cd2 / dg2;  // LOC_LOSS_WEIGHT = 1
  }

  __syncthreads();  // hc/hs zeroed before use
  if (!pos) {
    uint32_t kb = __float_as_uint(fl);
    atomicAdd(&hc[kb >> SHB], 1u);       // 256 keys into 2048 bins: ~conflict-free
    atomicAdd(&hs[kb >> SHB], fl);
  }

  float flp = pos ? fl : 0.0f;
  float np1 = pos ? 1.0f : 0.0f;
  for (int o = 32; o; o >>= 1) {
    locv += __shfl_down(locv, o);
    flp  += __shfl_down(flp, o);
    np1  += __shfl_down(np1, o);
  }
  __shared__ float sl[4], sf[4], sn[4];
  if ((threadIdx.x & 63) == 0) {
    int w = threadIdx.x >> 6;
    sl[w] = locv; sf[w] = flp; sn[w] = np1;
  }
  __syncthreads();
  // flush nonzero bins: <=512 global atomics per block, spread over per-image bins
  for (int i = threadIdx.x; i < NBIN; i += 256) {
    uint32_t c = hc[i];
    if (c) {
      atomicAdd(&hist_cnt[img * NBIN + i], c);
      atomicAdd(&hist_sum[img * NBIN + i], hs[i]);
    }
  }
  if (threadIdx.x == 0) {
    const int pi = img * 256 + bx;
    part_loc[pi] = sl[0] + sl[1] + sl[2] + sl[3];
    part_fl[pi]  = sf[0] + sf[1] + sf[2] + sf[3];
    part_np[pi]  = sn[0] + sn[1] + sn[2] + sn[3];  // integer-valued, exact
  }
}

// ---------------- K4: hist -> threshold bin -> exact k-th; last block does final combine ----------------
__global__ __launch_bounds__(1024) void dl_select(
    const uint32_t* __restrict__ negkey,
    const uint32_t* __restrict__ hist_cnt, const float* __restrict__ hist_sum,
    const float* __restrict__ part_loc, const float* __restrict__ part_fl,
    const float* __restrict__ part_np, float* __restrict__ acc,
    uint32_t* __restrict__ done_ctr, float* __restrict__ out) {
  const int img = blockIdx.x;
  const int t = threadIdx.x;
  const uint4* __restrict__ k4 = (const uint4*)(negkey + (size_t)img * A_N);
  const int N4 = A_N / 4;  // 16384

  __shared__ uint32_t cnt[NBIN];
  __shared__ float    bsum[NBIN];
  __shared__ uint32_t cbuf[CAP];
  __shared__ float s3[3][4];
  __shared__ float redf[16];
  __shared__ int   redi[16];
  __shared__ float np_sh, psum_sh, loc_sh, sstar_sh, negsum_sh;
  __shared__ uint32_t bstar_sh, cstar_sh, ccnt_sh;

  for (int i = t; i < NBIN; i += 1024) {
    cnt[i]  = hist_cnt[img * NBIN + i];
    bsum[i] = hist_sum[img * NBIN + i];
  }

  // ---- prologue: reduce the 256 per-block partials of this image ----
  float lv = 0.f, fv = 0.f, nv = 0.f;
  if (t < 256) {
    lv = part_loc[img * 256 + t];
    fv = part_fl[img * 256 + t];
    nv = part_np[img * 256 + t];
  }
  for (int o = 32; o; o >>= 1) {
    lv += __shfl_down(lv, o);
    fv += __shfl_down(fv, o);
    nv += __shfl_down(nv, o);
  }
  if (t < 256 && (t & 63) == 0) { s3[0][t >> 6] = lv; s3[1][t >> 6] = fv; s3[2][t >> 6] = nv; }
  __syncthreads();
  if (t == 0) {
    loc_sh  = s3[0][0] + s3[0][1] + s3[0][2] + s3[0][3];
    psum_sh = s3[1][0] + s3[1][1] + s3[1][2] + s3[1][3];
    np_sh   = s3[2][0] + s3[2][1] + s3[2][2] + s3[2][3];
    negsum_sh = 0.f;
  }
  __syncthreads();

  const int np = (int)(np_sh + 0.5f);
  const int k = min(A_N - np, 3 * np);

  if (k > 0) {
    // ---- wave 0: find threshold bin b*: C(b*) < k <= C(b*)+cnt[b*] ----
    if (t < 64) {
      const int CH = NBIN / 64;              // 32
      const int lob = NBIN - CH * (t + 1);   // lane 0 owns the TOP chunk
      uint32_t csum = 0;
      for (int b = lob; b < lob + CH; ++b) csum += cnt[b];
      uint32_t pre = csum;
      for (int o = 1; o < 64; o <<= 1) { uint32_t u = __shfl_up(pre, o); if (t >= o) pre += u; }
      uint32_t run = pre - csum;             // keys in bins above my chunk
      for (int b = lob + CH - 1; b >= lob; --b) {
        uint32_t c = cnt[b];
        if (run < (uint32_t)k && run + c >= (uint32_t)k) { bstar_sh = (uint32_t)b; cstar_sh = run; }
        run += c;
      }
    }
    __syncthreads();
    const int bstar = (int)bstar_sh;
    const uint32_t cstar = cstar_sh;
    const uint32_t cbin = cnt[bstar];
    const uint32_t r = (uint32_t)k - cstar;  // 1 <= r <= cbin

    // ---- Sstar = sum of all keys in bins > b* ----
    float s = 0.f;
    for (int i = t; i < NBIN; i += 1024) if (i > bstar) s += bsum[i];
    for (int o = 32; o; o >>= 1) s += __shfl_down(s, o);
    if ((t & 63) == 0) redf[t >> 6] = s;
    __syncthreads();
    if (t == 0) {
      float ss = 0.f;
      #pragma unroll
      for (int w = 0; w < 16; ++w) ss += redf[w];
      sstar_sh = ss;
    }
    __syncthreads();

    if (r == cbin) {
      if (t == 0) negsum_sh = sstar_sh + bsum[bstar];
    } else if (cbin <= (uint32_t)CAP) {
      // ---- compact boundary bin (typically ~50-300 keys), then wave-0 bisect 21 bits ----
      if (t == 0) ccnt_sh = 0u;
      __syncthreads();
      for (int i = t; i < N4; i += 1024) {
        uint4 v = k4[i];
        if ((v.x >> SHB) == (uint32_t)bstar) cbuf[atomicAdd(&ccnt_sh, 1u)] = v.x;
        if ((v.y >> SHB) == (uint32_t)bstar) cbuf[atomicAdd(&ccnt_sh, 1u)] = v.y;
        if ((v.z >> SHB) == (uint32_t)bstar) cbuf[atomicAdd(&ccnt_sh, 1u)] = v.z;
        if ((v.w >> SHB) == (uint32_t)bstar) cbuf[atomicAdd(&ccnt_sh, 1u)] = v.w;
      }
      __syncthreads();
      if (t < 64) {
        const int n = (int)ccnt_sh;
        uint32_t lo = (uint32_t)bstar << SHB;
        uint32_t hi = ((uint32_t)bstar + 1u) << SHB;
        while (hi - lo > 1u) {
          uint32_t mid = lo + ((hi - lo) >> 1);
          int c = 0;
          for (int i = t; i < n; i += 64) c += (cbuf[i] >= mid) ? 1 : 0;
          for (int o = 32; o; o >>= 1) c += __shfl_down(c, o);
          c = __shfl(c, 0);
          if ((uint32_t)c >= r) lo = mid; else hi = mid;
        }
        float s2 = 0.f; int cg = 0;
        for (int i = t; i < n; i += 64) {
          uint32_t x = cbuf[i];
          if (x > lo) { s2 += __uint_as_float(x); cg++; }
        }
        for (int o = 32; o; o >>= 1) { s2 += __shfl_down(s2, o); cg += __shfl_down(cg, o); }
        if (t == 0) negsum_sh = sstar_sh + s2 + (float)(int)(r - (uint32_t)cg) * __uint_as_float(lo);
      }
    } else {
      // ---- fallback (pathological tie bin): global bisection within the bin's range ----
      uint32_t lo = (uint32_t)bstar << SHB;
      uint32_t hi = ((uint32_t)bstar + 1u) << SHB;
      while (hi - lo > 1u) {
        uint32_t mid = lo + ((hi - lo) >> 1);
        int c = 0;
        for (int i = t; i < N4; i += 1024) {
          uint4 v = k4[i];
          c += (v.x >= mid) + (v.y >= mid) + (v.z >= mid) + (v.w >= mid);
        }
        for (int o = 32; o; o >>= 1) c += __shfl_down(c, o);
        if ((t & 63) == 0) redi[t >> 6] = c;
        __syncthreads();
        c = 0;
        #pragma unroll
        for (int w = 0; w < 16; ++w) c += redi[w];
        __syncthreads();
        if (c >= k) lo = mid; else hi = mid;
      }
      float s2 = 0.f; int cg = 0;
      for (int i = t; i < N4; i += 1024) {
        uint4 v = k4[i];
        if (v.x > lo) { s2 += __uint_as_float(v.x); cg++; }
        if (v.y > lo) { s2 += __uint_as_float(v.y); cg++; }
        if (v.z > lo) { s2 += __uint_as_float(v.z); cg++; }
        if (v.w > lo) { s2 += __uint_as_float(v.w); cg++; }
      }
      for (int o = 32; o; o >>= 1) { s2 += __shfl_down(s2, o); cg += __shfl_down(cg, o); }
      if ((t & 63) == 0) { redf[t >> 6] = s2; redi[t >> 6] = cg; }
      __syncthreads();
      if (t == 0) {
        float ss = 0.f; int cc = 0;
        #pragma unroll
        for (int w = 0; w < 16; ++w) { ss += redf[w]; cc += redi[w]; }
        negsum_sh = ss + (float)(k - cc) * __uint_as_float(lo);
      }
    }
  }
  __syncthreads();
  if (t == 0) {
    acc[img] = loc_sh;
    acc[32 + img] = (float)np;
    acc[48 + img] = (psum_sh + negsum_sh) / fmaxf((float)(np + k), 1.0f);
    // ---- last-block finale (replaces dl_final): fence + device-scope counter ----
    __threadfence();
    uint32_t old = atomicAdd(done_ctr, 1u);
    if (old == (uint32_t)(B_N - 1)) {
      __threadfence();
      float sl = 0.f, sc = 0.f, sn = 0.f;
      for (int i = 0; i < B_N; ++i) {
        sl += acc[i];
        sc += acc[48 + i];
        sn += acc[32 + i];
      }
      float tp = fmaxf(sn, 1.0f);
      float al = sl / tp;
      float ac = sc / tp;
      out[0] = al + ac;
      out[1] = ac;
      out[2] = al;
    }
  }
}

extern "C" void kernel_launch(void* const* d_in, const int* in_sizes, int n_in,
                              void* d_out, int out_size, void* d_ws, size_t ws_size,
                              hipStream_t stream) {
  (void)in_sizes; (void)n_in; (void)out_size; (void)ws_size;

  const float4* bbox = (const float4*)d_in[0];   // [B, A, 4] f32
  const float*  conf = (const float*)d_in[1];    // [B, A] f32
  const float4* gt   = (const float4*)d_in[2];   // [B, G, 4] f32
  float* out = (float*)d_out;

  char* ws = (char*)d_ws;
  const size_t SZ = (size_t)B_N * A_N * 4;                 // 4 MiB
  float*              posflag  = (float*)(ws);             // 4 MiB
  uint32_t*           negkey   = (uint32_t*)(ws + SZ);     // 4 MiB
  unsigned long long* gt_part  = (unsigned long long*)(ws + 2 * SZ);          // 2 MiB
  uint8_t*            best_idx = (uint8_t*)(ws + 2 * SZ + (size_t)B_N * 256 * G_N * 8);  // 1 MiB
  char* hb = ws + 2 * SZ + (size_t)B_N * 256 * G_N * 8 + (size_t)B_N * A_N;
  uint32_t* hist_cnt = (uint32_t*)(hb);                    // 128 KiB  [16][2048]
  float*    hist_sum = (float*)(hb + (size_t)B_N * NBIN * 4);  // 128 KiB
  char* tail = hb + 2 * (size_t)B_N * NBIN * 4;
  float* part_loc = (float*)(tail);                        // 16 KiB
  float* part_fl  = (float*)(tail + 16384);
  float* part_np  = (float*)(tail + 32768);
  float* acc      = (float*)(tail + 49152);                // 64 floats
  uint32_t* done_ctr = (uint32_t*)(tail + 49152 + 256);

  dl_pass1<<<dim3(A_N / 256, B_N), 256, 0, stream>>>(bbox, gt, posflag, best_idx, gt_part,
                                                     hist_cnt /* zeroes cnt+sum */, done_ctr);
  dl_force<<<B_N * G_N, 64, 0, stream>>>(gt_part, posflag);
  dl_pass2<<<dim3(A_N / 256, B_N), 256, 0, stream>>>(bbox, conf, gt, posflag, best_idx,
                                                     negkey, hist_cnt, hist_sum,
                                                     part_loc, part_fl, part_np);
  dl_select<<<B_N, 1024, 0, stream>>>(negkey, hist_cnt, hist_sum,
                                      part_loc, part_fl, part_np, acc, done_ctr, out);
}

// Round 6
// 172.653 us; speedup vs baseline: 1.5107x; 1.0622x over previous
//
#include <hip/hip_runtime.h>
#include <stdint.h>

#define A_N 65536
#define B_N 16
#define G_N 64
#define FEPS 1e-7f

#define NBIN 2048
#define SHB  21      // bin = keybits >> 21  (sign + 8 exp + 2 mantissa bits)
#define CAP  6144

// focal loss for one logit/target (tolerance path — plain ops)
__device__ __forceinline__ float focal_one(float l, float tt) {
  float ce = fmaxf(l, 0.0f) - l * tt + log1pf(expf(-fabsf(l)));
  float pp = 1.0f / (1.0f + expf(-l));
  float pt = pp * tt + (1.0f - pp) * (1.0f - tt);
  pt = fminf(fmaxf(pt, FEPS), 1.0f - FEPS);
  float om = 1.0f - pt;
  float alpha = tt > 0.5f ? 0.25f : 0.75f;
  return alpha * om * om * ce;
}

// DIoU loss for one (pred, gt) pair (tolerance path)
__device__ __forceinline__ float diou_one(float4 p, float4 q) {
  float ap = (p.z - p.x) * (p.w - p.y);
  float ag = (q.z - q.x) * (q.w - q.y);
  float ix1 = fmaxf(p.x, q.x), iy1 = fmaxf(p.y, q.y);
  float ix2 = fminf(p.z, q.z), iy2 = fminf(p.w, q.w);
  float iw = fmaxf(ix2 - ix1, 0.0f), ih = fmaxf(iy2 - iy1, 0.0f);
  float inter = iw * ih;
  float iou = inter / (ap + ag - inter + FEPS);
  float cpx = (p.x + p.z) * 0.5f, cpy = (p.y + p.w) * 0.5f;
  float cgx = (q.x + q.z) * 0.5f, cgy = (q.y + q.w) * 0.5f;
  float dx = cpx - cgx, dy = cpy - cgy;
  float cd2 = dx * dx + dy * dy;
  float ex1 = fminf(p.x, q.x), ey1 = fminf(p.y, q.y);
  float ex2 = fmaxf(p.z, q.z), ey2 = fmaxf(p.w, q.w);
  float ddx = ex2 - ex1, ddy = ey2 - ey1;
  float dg2 = ddx * ddx + ddy * ddy + FEPS;
  return 1.0f - iou + cd2 / dg2;   // LOC_LOSS_WEIGHT = 1
}

// ---------------- K0: zero global hist (cnt+sum contiguous, 65536 words) + done_ctr ----------------
__global__ void dl_init(uint32_t* __restrict__ histz, uint32_t* __restrict__ done_ctr) {
  int i = blockIdx.x * 1024 + threadIdx.x;
  histz[i] = 0u;
  if (i == 0) *done_ctr = 0u;
}

// ---------------- K1: matching (row argmax + rotating column argmax) FUSED with
// focal/negkey/DIoU/hist/partials — one pass over all anchors ----------------
__global__ __launch_bounds__(256) void dl_pass1(
    const float4* __restrict__ bbox, const float* __restrict__ conf,
    const float4* __restrict__ gt,
    uint8_t* __restrict__ best_idx, uint32_t* __restrict__ negkey,
    unsigned long long* __restrict__ gt_part,
    uint32_t* __restrict__ hist_cnt, float* __restrict__ hist_sum,
    float* __restrict__ part_loc, float* __restrict__ part_fl, float* __restrict__ part_np) {
  const int img = blockIdx.y;
  const int bx  = blockIdx.x;
  const int t   = threadIdx.x;
  const int wave = t >> 6, lane = t & 63;
  const int a = bx * 256 + t;
  const int idx = img * A_N + a;

  __shared__ float4 sg[G_N];
  __shared__ float  sga[G_N];
  __shared__ unsigned long long spart[4][G_N];
  __shared__ uint32_t hc[NBIN];
  __shared__ float    hs[NBIN];
  __shared__ float sl[4], sf[4], sn[4];

  for (int i = t; i < NBIN; i += 256) { hc[i] = 0u; hs[i] = 0.f; }
  if (t < G_N) {
    float4 q0 = gt[img * G_N + t];
    sg[t] = q0;
    // exact f32, no contraction (matches numpy bit-for-bit)
    sga[t] = __fmul_rn(__fsub_rn(q0.z, q0.x), __fsub_rn(q0.w, q0.y));
  }
  __syncthreads();

  float4 p = bbox[idx];
  float pa = __fmul_rn(__fsub_rn(p.z, p.x), __fsub_rn(p.w, p.y));
  float l = conf[idx];

  float bi = 0.f, bd = 1.f; int bidx = 0; float posm = -1.f;
  uint32_t colkey = 0u;                       // rotating column-max register
  const int rotsrc = (lane + 1) & 63;         // pull from next lane after each iter
  const uint32_t lanecomp = 63u - (uint32_t)lane;  // smaller lane wins ties under max

  int g = lane;
  #pragma unroll 4
  for (int j = 0; j < G_N; ++j) {
    float4 q = sg[g];
    float qa = sga[g];
    float ix1 = fmaxf(p.x, q.x), iy1 = fmaxf(p.y, q.y);
    float ix2 = fminf(p.z, q.z), iy2 = fminf(p.w, q.w);
    float iw = fmaxf(__fsub_rn(ix2, ix1), 0.f);
    float ih = fmaxf(__fsub_rn(iy2, iy1), 0.f);
    float inter = __fmul_rn(iw, ih);
    float den = __fadd_rn(__fsub_rn(__fadd_rn(pa, qa), inter), FEPS);  // exact numpy den
    // row argmax via cross-mult (no division); strict > keeps first-occurrence semantics
    if (inter * bd > bi * den) { bi = inter; bd = den; bidx = g; }
    // pos threshold EXACT: iou > 0.5 <=> sign(2*inter - den) > 0 (RN preserves sign)
    posm = fmaxf(posm, __fmaf_rn(2.f, inter, -den));
    // column candidate: approx ratio (1-ulp rcp), top 26 bits | lane-complement
    float ratio = inter * __builtin_amdgcn_rcpf(den);
    uint32_t key = (__float_as_uint(ratio) & 0xFFFFFFC0u) | lanecomp;
    if (key > colkey) colkey = key;
    colkey = __shfl(colkey, rotsrc);          // register now belongs to g+1
    g = (g + 1) & 63;
  }

  const bool pos = posm > 0.f;
  best_idx[idx] = (uint8_t)bidx;

  // ---- fused focal + negkey + DIoU (matched gt is already in LDS) ----
  float fl = focal_one(l, pos ? 1.0f : 0.0f);
  negkey[idx] = pos ? 0u : __float_as_uint(fl);  // fl > 0 strictly; 0 sentinel below all negatives
  float locv = pos ? diou_one(p, sg[bidx]) : 0.0f;
  if (!pos) {
    uint32_t kb = __float_as_uint(fl);
    atomicAdd(&hc[kb >> SHB], 1u);       // 256 keys into 2048 bins: ~conflict-free
    atomicAdd(&hs[kb >> SHB], fl);
  }

  // lane l holds the wave's column max for gt l; build cross-block comparable u64 key
  uint32_t winlane = 63u - (colkey & 63u);
  uint32_t ganchor = (uint32_t)(bx * 256 + wave * 64) + winlane;
  unsigned long long wkey = ((unsigned long long)(colkey & 0xFFFFFFC0u) << 32)
                          | (unsigned)~ganchor;  // smaller global idx wins ties
  spart[wave][lane] = wkey;

  // per-wave partials
  float flp = pos ? fl : 0.0f;
  float np1 = pos ? 1.0f : 0.0f;
  float lv = locv;
  for (int o = 32; o; o >>= 1) {
    lv  += __shfl_down(lv, o);
    flp += __shfl_down(flp, o);
    np1 += __shfl_down(np1, o);
  }
  if (lane == 0) { sl[wave] = lv; sf[wave] = flp; sn[wave] = np1; }
  __syncthreads();

  // flush nonzero hist bins (~60 hot bins/block), gt partial, block partials
  for (int i = t; i < NBIN; i += 256) {
    uint32_t c = hc[i];
    if (c) {
      atomicAdd(&hist_cnt[img * NBIN + i], c);
      atomicAdd(&hist_sum[img * NBIN + i], hs[i]);
    }
  }
  if (t < G_N) {
    unsigned long long m = spart[0][t];
    if (spart[1][t] > m) m = spart[1][t];
    if (spart[2][t] > m) m = spart[2][t];
    if (spart[3][t] > m) m = spart[3][t];
    gt_part[(((size_t)(img << 8) | bx) << 6) | t] = m;  // coalesced 512B store
  }
  if (t == 0) {
    const int pi = img * 256 + bx;
    part_loc[pi] = sl[0] + sl[1] + sl[2] + sl[3];
    part_fl[pi]  = sf[0] + sf[1] + sf[2] + sf[3];
    part_np[pi]  = sn[0] + sn[1] + sn[2] + sn[3];  // integer-valued, exact
  }
}

// ---------------- K2: force+fixup + partial reduce + exact top-k + finale ----------------
__global__ __launch_bounds__(1024) void dl_select(
    uint32_t* negkey,   // no __restrict__: aliased as uint4 below
    const unsigned long long* __restrict__ gt_part,
    const uint32_t* __restrict__ hist_cnt, const float* __restrict__ hist_sum,
    const float* __restrict__ part_loc, const float* __restrict__ part_fl,
    const float* __restrict__ part_np,
    const float4* __restrict__ bbox, const float* __restrict__ conf,
    const float4* __restrict__ gt, const uint8_t* __restrict__ best_idx,
    float* __restrict__ acc, uint32_t* __restrict__ done_ctr, float* __restrict__ out) {
  const int img = blockIdx.x;
  const int t = threadIdx.x;
  uint32_t* negk = negkey + (size_t)img * A_N;
  const uint4* k4 = (const uint4*)negk;
  const int N4 = A_N / 4;  // 16384

  __shared__ uint32_t cnt[NBIN];
  __shared__ float    bsum[NBIN];
  __shared__ uint32_t cbuf[CAP];
  __shared__ unsigned long long gred[16][G_N];
  __shared__ float s3[3][4];
  __shared__ float redf[16];
  __shared__ int   redi[16];
  __shared__ float np_sh, psum_sh, loc_sh, sstar_sh, negsum_sh;
  __shared__ float fix_l, fix_f, fix_n;
  __shared__ uint32_t bstar_sh, cstar_sh, ccnt_sh;

  // ---- region A: load hist, stage gt_part partial-max, reduce block partials ----
  for (int i = t; i < NBIN; i += 1024) {
    cnt[i]  = hist_cnt[img * NBIN + i];
    bsum[i] = hist_sum[img * NBIN + i];
  }
  {
    const int g = t & 63, ch = t >> 6;   // 16 chunks x 64 gts
    unsigned long long m = 0ull;
    #pragma unroll 4
    for (int j = 0; j < 16; ++j) {
      unsigned long long v = gt_part[(((size_t)(img << 8) | (ch * 16 + j)) << 6) | g];
      if (v > m) m = v;
    }
    gred[ch][g] = m;
  }
  float lv = 0.f, fv = 0.f, nv = 0.f;
  if (t < 256) {
    lv = part_loc[img * 256 + t];
    fv = part_fl[img * 256 + t];
    nv = part_np[img * 256 + t];
  }
  for (int o = 32; o; o >>= 1) {
    lv += __shfl_down(lv, o);
    fv += __shfl_down(fv, o);
    nv += __shfl_down(nv, o);
  }
  if (t < 256 && (t & 63) == 0) { s3[0][t >> 6] = lv; s3[1][t >> 6] = fv; s3[2][t >> 6] = nv; }
  __syncthreads();

  // ---- region B (wave 0): per-gt final argmax + forced-positive fixup ----
  if (t < 64) {
    unsigned long long m = gred[0][t];
    #pragma unroll
    for (int c = 1; c < 16; ++c) if (gred[c][t] > m) m = gred[c][t];
    // all-zero column: ratio bits 0 for every anchor -> max low-word = ~0 -> anchor 0 (numpy argmax)
    uint32_t a = ~(uint32_t)(m & 0xFFFFFFFFull);
    // dedupe multiple gts forcing the same anchor; also skips already-positive anchors
    uint32_t old = atomicExch(&negk[a], 0u);
    float dl = 0.f, df = 0.f, dn = 0.f;
    if (old != 0u) {
      dn = 1.f;
      float fln = __uint_as_float(old);
      uint32_t bin = old >> SHB;
      atomicSub(&cnt[bin], 1u);          // remove from negative hist
      atomicAdd(&bsum[bin], -fln);
      const int ai = img * A_N + (int)a;
      df = focal_one(conf[ai], 1.0f);    // now a positive
      dl = diou_one(bbox[ai], gt[img * G_N + best_idx[ai]]);
    }
    for (int o = 32; o; o >>= 1) {
      dl += __shfl_down(dl, o);
      df += __shfl_down(df, o);
      dn += __shfl_down(dn, o);
    }
    if (t == 0) { fix_l = dl; fix_f = df; fix_n = dn; }
  }
  __threadfence();
  __syncthreads();

  if (t == 0) {
    loc_sh  = s3[0][0] + s3[0][1] + s3[0][2] + s3[0][3] + fix_l;
    psum_sh = s3[1][0] + s3[1][1] + s3[1][2] + s3[1][3] + fix_f;
    np_sh   = s3[2][0] + s3[2][1] + s3[2][2] + s3[2][3] + fix_n;
    negsum_sh = 0.f;
  }
  __syncthreads();

  const int np = (int)(np_sh + 0.5f);
  const int k = min(A_N - np, 3 * np);

  if (k > 0) {
    // ---- wave 0: find threshold bin b*: C(b*) < k <= C(b*)+cnt[b*] ----
    if (t < 64) {
      const int CH = NBIN / 64;              // 32
      const int lob = NBIN - CH * (t + 1);   // lane 0 owns the TOP chunk
      uint32_t csum = 0;
      for (int b = lob; b < lob + CH; ++b) csum += cnt[b];
      uint32_t pre = csum;
      for (int o = 1; o < 64; o <<= 1) { uint32_t u = __shfl_up(pre, o); if (t >= o) pre += u; }
      uint32_t run = pre - csum;             // keys in bins above my chunk
      for (int b = lob + CH - 1; b >= lob; --b) {
        uint32_t c = cnt[b];
        if (run < (uint32_t)k && run + c >= (uint32_t)k) { bstar_sh = (uint32_t)b; cstar_sh = run; }
        run += c;
      }
    }
    __syncthreads();
    const int bstar = (int)bstar_sh;
    const uint32_t cstar = cstar_sh;
    const uint32_t cbin = cnt[bstar];
    const uint32_t r = (uint32_t)k - cstar;  // 1 <= r <= cbin

    // ---- Sstar = sum of all keys in bins > b* ----
    float s = 0.f;
    for (int i = t; i < NBIN; i += 1024) if (i > bstar) s += bsum[i];
    for (int o = 32; o; o >>= 1) s += __shfl_down(s, o);
    if ((t & 63) == 0) redf[t >> 6] = s;
    __syncthreads();
    if (t == 0) {
      float ss = 0.f;
      #pragma unroll
      for (int w = 0; w < 16; ++w) ss += redf[w];
      sstar_sh = ss;
    }
    __syncthreads();

    if (r == cbin) {
      if (t == 0) negsum_sh = sstar_sh + bsum[bstar];
    } else if (cbin <= (uint32_t)CAP) {
      // ---- compact boundary bin (typically ~50-300 keys), then wave-0 bisect 21 bits ----
      if (t == 0) ccnt_sh = 0u;
      __syncthreads();
      for (int i = t; i < N4; i += 1024) {
        uint4 v = k4[i];
        if ((v.x >> SHB) == (uint32_t)bstar) cbuf[atomicAdd(&ccnt_sh, 1u)] = v.x;
        if ((v.y >> SHB) == (uint32_t)bstar) cbuf[atomicAdd(&ccnt_sh, 1u)] = v.y;
        if ((v.z >> SHB) == (uint32_t)bstar) cbuf[atomicAdd(&ccnt_sh, 1u)] = v.z;
        if ((v.w >> SHB) == (uint32_t)bstar) cbuf[atomicAdd(&ccnt_sh, 1u)] = v.w;
      }
      __syncthreads();
      if (t < 64) {
        const int n = (int)ccnt_sh;
        uint32_t lo = (uint32_t)bstar << SHB;
        uint32_t hi = ((uint32_t)bstar + 1u) << SHB;
        while (hi - lo > 1u) {
          uint32_t mid = lo + ((hi - lo) >> 1);
          int c = 0;
          for (int i = t; i < n; i += 64) c += (cbuf[i] >= mid) ? 1 : 0;
          for (int o = 32; o; o >>= 1) c += __shfl_down(c, o);
          c = __shfl(c, 0);
          if ((uint32_t)c >= r) lo = mid; else hi = mid;
        }
        float s2 = 0.f; int cg = 0;
        for (int i = t; i < n; i += 64) {
          uint32_t x = cbuf[i];
          if (x > lo) { s2 += __uint_as_float(x); cg++; }
        }
        for (int o = 32; o; o >>= 1) { s2 += __shfl_down(s2, o); cg += __shfl_down(cg, o); }
        if (t == 0) negsum_sh = sstar_sh + s2 + (float)(int)(r - (uint32_t)cg) * __uint_as_float(lo);
      }
    } else {
      // ---- fallback (pathological tie bin): global bisection within the bin's range ----
      uint32_t lo = (uint32_t)bstar << SHB;
      uint32_t hi = ((uint32_t)bstar + 1u) << SHB;
      while (hi - lo > 1u) {
        uint32_t mid = lo + ((hi - lo) >> 1);
        int c = 0;
        for (int i = t; i < N4; i += 1024) {
          uint4 v = k4[i];
          c += (v.x >= mid) + (v.y >= mid) + (v.z >= mid) + (v.w >= mid);
        }
        for (int o = 32; o; o >>= 1) c += __shfl_down(c, o);
        if ((t & 63) == 0) redi[t >> 6] = c;
        __syncthreads();
        c = 0;
        #pragma unroll
        for (int w = 0; w < 16; ++w) c += redi[w];
        __syncthreads();
        if (c >= k) lo = mid; else hi = mid;
      }
      float s2 = 0.f; int cg = 0;
      for (int i = t; i < N4; i += 1024) {
        uint4 v = k4[i];
        if (v.x > lo) { s2 += __uint_as_float(v.x); cg++; }
        if (v.y > lo) { s2 += __uint_as_float(v.y); cg++; }
        if (v.z > lo) { s2 += __uint_as_float(v.z); cg++; }
        if (v.w > lo) { s2 += __uint_as_float(v.w); cg++; }
      }
      for (int o = 32; o; o >>= 1) { s2 += __shfl_down(s2, o); cg += __shfl_down(cg, o); }
      if ((t & 63) == 0) { redf[t >> 6] = s2; redi[t >> 6] = cg; }
      __syncthreads();
      if (t == 0) {
        float ss = 0.f; int cc = 0;
        #pragma unroll
        for (int w = 0; w < 16; ++w) { ss += redf[w]; cc += redi[w]; }
        negsum_sh = ss + (float)(k - cc) * __uint_as_float(lo);
      }
    }
  }
  __syncthreads();
  if (t == 0) {
    acc[img] = loc_sh;
    acc[32 + img] = (float)np;
    acc[48 + img] = (psum_sh + negsum_sh) / fmaxf((float)(np + k), 1.0f);
    // ---- last-block finale: fence + device-scope counter ----
    __threadfence();
    uint32_t old = atomicAdd(done_ctr, 1u);
    if (old == (uint32_t)(B_N - 1)) {
      __threadfence();
      float sl = 0.f, sc = 0.f, sn = 0.f;
      for (int i = 0; i < B_N; ++i) {
        sl += acc[i];
        sc += acc[48 + i];
        sn += acc[32 + i];
      }
      float tp = fmaxf(sn, 1.0f);
      float al = sl / tp;
      float ac = sc / tp;
      out[0] = al + ac;
      out[1] = ac;
      out[2] = al;
    }
  }
}

extern "C" void kernel_launch(void* const* d_in, const int* in_sizes, int n_in,
                              void* d_out, int out_size, void* d_ws, size_t ws_size,
                              hipStream_t stream) {
  (void)in_sizes; (void)n_in; (void)out_size; (void)ws_size;

  const float4* bbox = (const float4*)d_in[0];   // [B, A, 4] f32
  const float*  conf = (const float*)d_in[1];    // [B, A] f32
  const float4* gt   = (const float4*)d_in[2];   // [B, G, 4] f32
  float* out = (float*)d_out;

  char* ws = (char*)d_ws;
  uint32_t*           negkey   = (uint32_t*)(ws);                       // 4 MiB
  unsigned long long* gt_part  = (unsigned long long*)(ws + (4u << 20));// 2 MiB [16][256][64]
  uint8_t*            best_idx = (uint8_t*)(ws + (6u << 20));          // 1 MiB
  char* hb = ws + (7u << 20);
  uint32_t* hist_cnt = (uint32_t*)(hb);                                // 128 KiB [16][2048]
  float*    hist_sum = (float*)(hb + (size_t)B_N * NBIN * 4);          // 128 KiB (contiguous after cnt)
  char* tail = hb + 2 * (size_t)B_N * NBIN * 4;
  float* part_loc = (float*)(tail);                                    // 16 KiB
  float* part_fl  = (float*)(tail + 16384);
  float* part_np  = (float*)(tail + 32768);
  float* acc      = (float*)(tail + 49152);                            // 64 floats
  uint32_t* done_ctr = (uint32_t*)(tail + 49152 + 256);

  dl_init<<<64, 1024, 0, stream>>>(hist_cnt /* zeroes cnt+sum (contiguous) */, done_ctr);
  dl_pass1<<<dim3(A_N / 256, B_N), 256, 0, stream>>>(bbox, conf, gt, best_idx, negkey,
                                                     gt_part, hist_cnt, hist_sum,
                                                     part_loc, part_fl, part_np);
  dl_select<<<B_N, 1024, 0, stream>>>(negkey, gt_part, hist_cnt, hist_sum,
                                      part_loc, part_fl, part_np,
                                      bbox, conf, gt, best_idx, acc, done_ctr, out);
}